// Round 23
// baseline (477.009 us; speedup 1.0000x reference)
//
#include <hip/hip_runtime.h>
#include <hip/hip_bf16.h>

#define M_TOTAL (32 * 64 * 64)   // 131072 rows
#define CDIM 256
#define HDIM 1024

typedef float  floatx4 __attribute__((ext_vector_type(4)));
typedef short  short8  __attribute__((ext_vector_type(8)));

// ---------------------------------------------------------------------------
// frag_pack: convert fp32 weight [K][N] (row-major) into fragment-major bf16:
//   dst16B[g][kk][lane] = { src[kk*32 + (lane>>4)*8 + e][g*16 + (lane&15)] }
// so one wave's B-fragment (64 lanes x 16B) is one CONTIGUOUS 1KB block.
// ---------------------------------------------------------------------------
__global__ __launch_bounds__(256) void frag_pack(
    const float* __restrict__ src, __hip_bfloat16* __restrict__ dst,
    int K, int N)
{
    const int idx  = blockIdx.x * 256 + threadIdx.x;   // one 16B frag / thread
    const int lane = idx & 63;
    const int nkk  = K >> 5;
    const int kk   = (idx >> 6) % nkk;
    const int g    = idx / (nkk << 6);
    const int col  = g * 16 + (lane & 15);
    const int k0   = kk * 32 + (lane >> 4) * 8;
    union { short8 v; __hip_bfloat16 h[8]; } p;
#pragma unroll
    for (int e = 0; e < 8; ++e)
        p.h[e] = __float2bfloat16(src[(long)(k0 + e) * N + col]);
    ((short8*)dst)[idx] = p.v;
}

// fast GELU (tanh form), max dev vs erf-GELU ~1e-3 (validated R2-R22)
__device__ __forceinline__ float gelu_fast(float v)
{
    const float t = v * __builtin_fmaf(v * v, 0.044715f, 1.0f);
    const float e = __expf(t * -1.5957691216f);
    return v * __builtin_amdgcn_rcpf(1.0f + e);
}

// ---------------------------------------------------------------------------
// Fused Swin block, R23 = R18/R22 with waves re-tiled 1x8 -> 2x4 (row-groups
// x col-groups) to halve LDS-read traffic — the largest accounted pipe
// (~123us of 321: 48 ds_read_b128/chunk/wave with zero A-frag nf-reuse).
//   Per wave now: rows wm*32..+32; fc1 cols wn*32+nf*16 (nf<2, A-frag feeds
//   2 MFMA); fc2 cols wn*64+nf*16 (nf<4, A-frag feeds 4 MFMA).
//   LDS reads/chunk/wave: 48 -> 24.  MFMA count/wave unchanged (32+32).
//   Weight frag loads double (1KB coalesced L2 hits — L2 has headroom).
//   Same k-order / chunk-128 / fp32-xn numerics family as all passing rounds.
//   LDS = As 32KB + single Hs 16KB = 48KB -> 3 blocks/CU; (512,4).
// Frag conventions verified R1-R22: A/B k-map slot=kf*4+fq, elem k&7,
// row/col=fr; C/D col=lane&15, row=(lane>>4)*4+reg.
// ---------------------------------------------------------------------------
__global__ __launch_bounds__(512, 4) void swin_fused(
    const float* __restrict__ x,
    const float* __restrict__ ln1g, const float* __restrict__ ln1b,
    const float* __restrict__ ln2g, const float* __restrict__ ln2b,
    const short8* __restrict__ w1f, const float* __restrict__ fb1,
    const short8* __restrict__ w2f, const float* __restrict__ fb2,
    float* __restrict__ xnbuf, float* __restrict__ out)
{
    __shared__ __align__(16) __hip_bfloat16 As[16384];   // 32 KB [slot32][row64][8]
    __shared__ __align__(16) __hip_bfloat16 Hs[8192];    // 16 KB [slot16][row64][8]

    const int  tid = threadIdx.x;
    const long m0  = (long)blockIdx.x * 64;

    // ---------------- LN phase: 8 threads per row ----------
    {
        const int row  = tid >> 3;        // 0..63
        const int part = tid & 7;         // 32-element segment
        const float* xr = x + (m0 + row) * CDIM + part * 32;

        float4 v[8];
        float s = 0.f, sq = 0.f;
#pragma unroll
        for (int i = 0; i < 8; ++i) {
            v[i] = ((const float4*)xr)[i];
            s  += v[i].x + v[i].y + v[i].z + v[i].w;
            sq += v[i].x*v[i].x + v[i].y*v[i].y + v[i].z*v[i].z + v[i].w*v[i].w;
        }
        s  += __shfl_xor(s, 1);  s  += __shfl_xor(s, 2);  s  += __shfl_xor(s, 4);
        sq += __shfl_xor(sq, 1); sq += __shfl_xor(sq, 2); sq += __shfl_xor(sq, 4);
        const float mu = s * (1.f / CDIM);
        const float rs = rsqrtf(sq * (1.f / CDIM) - mu * mu + 1e-5f);

        float s2 = 0.f, q2 = 0.f;
        float* xnp = xnbuf + (m0 + row) * CDIM + part * 32;
#pragma unroll
        for (int i = 0; i < 8; ++i) {
            const float4 G = ((const float4*)(ln1g + part * 32))[i];
            const float4 B = ((const float4*)(ln1b + part * 32))[i];
            v[i].x += (v[i].x - mu) * rs * G.x + B.x;
            v[i].y += (v[i].y - mu) * rs * G.y + B.y;
            v[i].z += (v[i].z - mu) * rs * G.z + B.z;
            v[i].w += (v[i].w - mu) * rs * G.w + B.w;
            s2 += v[i].x + v[i].y + v[i].z + v[i].w;
            q2 += v[i].x*v[i].x + v[i].y*v[i].y + v[i].z*v[i].z + v[i].w*v[i].w;
            ((float4*)xnp)[i] = v[i];
        }
        s2 += __shfl_xor(s2, 1); s2 += __shfl_xor(s2, 2); s2 += __shfl_xor(s2, 4);
        q2 += __shfl_xor(q2, 1); q2 += __shfl_xor(q2, 2); q2 += __shfl_xor(q2, 4);
        const float mu2 = s2 * (1.f / CDIM);
        const float rs2 = rsqrtf(q2 * (1.f / CDIM) - mu2 * mu2 + 1e-5f);

        // ln2 -> As fragment layout: slot=(k>>5)*4+((k>>3)&3), elem k&7
#pragma unroll
        for (int i = 0; i < 8; ++i) {
            const int col0 = part * 32 + i * 4;
            const float4 G = ((const float4*)(ln2g + part * 32))[i];
            const float4 B = ((const float4*)(ln2b + part * 32))[i];
            union { ushort4 u; __hip_bfloat16 h[4]; } p;
            p.h[0] = __float2bfloat16((v[i].x - mu2) * rs2 * G.x + B.x);
            p.h[1] = __float2bfloat16((v[i].y - mu2) * rs2 * G.y + B.y);
            p.h[2] = __float2bfloat16((v[i].z - mu2) * rs2 * G.z + B.z);
            p.h[3] = __float2bfloat16((v[i].w - mu2) * rs2 * G.w + B.w);
            const int idx16 = ((col0 >> 5) * 4 + ((col0 >> 3) & 3)) * 64 + row;
            *(ushort4*)(As + idx16 * 8 + (col0 & 7)) = p.u;
        }
    }
    __syncthreads();

    // ---------------- MLP phase (8 chunks of 128 hidden cols) -------------
    const int wave = tid >> 6;
    const int lane = tid & 63;
    const int wm = wave >> 2;           // row-group 0..1  (rows wm*32..+32)
    const int wn = wave & 3;            // col-group 0..3
    const int fr = lane & 15, fq = lane >> 4;

    floatx4 acc2[2][4] = {};            // 32 rows x 64 out-cols per wave

    float fb2w[4];
#pragma unroll
    for (int nf = 0; nf < 4; ++nf) fb2w[nf] = fb2[wn * 64 + nf * 16 + fr];

    // fragment-major bases:
    //   fc1 frag (chunk c, kf, nf): w1f[((c*8 + wn*2+nf)*8 + kf)*64 + lane]
    //   fc2 frag (chunk c, kf, nf): w2f[((wn*4+nf)*32 + c*4 + kf)*64 + lane]

#pragma unroll 2
    for (int c = 0; c < 8; ++c) {
        // ---- fc1: 2 mf x 2 nf, A-frag reused across nf ----
        float bb1[2];
#pragma unroll
        for (int nf = 0; nf < 2; ++nf)
            bb1[nf] = fb1[c * 128 + wn * 32 + nf * 16 + fr];

        floatx4 acc1[2][2];
#pragma unroll
        for (int mf = 0; mf < 2; ++mf)
#pragma unroll
            for (int nf = 0; nf < 2; ++nf)
                acc1[mf][nf] = (floatx4){0.f, 0.f, 0.f, 0.f};
#pragma unroll
        for (int kf = 0; kf < 8; ++kf) {
            short8 b[2];
#pragma unroll
            for (int nf = 0; nf < 2; ++nf)
                b[nf] = w1f[((c * 8 + wn * 2 + nf) * 8 + kf) * 64 + lane];
            short8 a[2];
#pragma unroll
            for (int mf = 0; mf < 2; ++mf)
                a[mf] = *(const short8*)(
                    As + ((kf * 4 + fq) * 64 + wm * 32 + mf * 16 + fr) * 8);
#pragma unroll
            for (int mf = 0; mf < 2; ++mf)
#pragma unroll
                for (int nf = 0; nf < 2; ++nf)
                    acc1[mf][nf] = __builtin_amdgcn_mfma_f32_16x16x32_bf16(
                        a[mf], b[nf], acc1[mf][nf], 0, 0, 0);
        }

        __syncthreads();   // all waves' FC2(c-1) Hs reads complete

        // ---- GELU + bias -> Hs (rows wm*32..+32, cols wn*32+nf*16) ----
#pragma unroll
        for (int nf = 0; nf < 2; ++nf) {
            const int col = wn * 32 + nf * 16 + fr;
            __hip_bfloat16* hp =
                Hs + (((col >> 5) * 4 + ((col >> 3) & 3)) * 64) * 8 + (col & 7);
#pragma unroll
            for (int mf = 0; mf < 2; ++mf)
#pragma unroll
                for (int j = 0; j < 4; ++j) {
                    const int row = wm * 32 + mf * 16 + fq * 4 + j;
                    hp[row * 8] = __float2bfloat16(gelu_fast(acc1[mf][nf][j] + bb1[nf]));
                }
        }
        __syncthreads();   // Hs ready for all waves

        // ---- fc2 partial: 2 mf x 4 nf, A-frag reused across nf ----
#pragma unroll
        for (int kf = 0; kf < 4; ++kf) {
            short8 bw[4];
#pragma unroll
            for (int nf = 0; nf < 4; ++nf)
                bw[nf] = w2f[((wn * 4 + nf) * 32 + c * 4 + kf) * 64 + lane];
            short8 ha[2];
#pragma unroll
            for (int mf = 0; mf < 2; ++mf)
                ha[mf] = *(const short8*)(
                    Hs + ((kf * 4 + fq) * 64 + wm * 32 + mf * 16 + fr) * 8);
#pragma unroll
            for (int mf = 0; mf < 2; ++mf)
#pragma unroll
                for (int nf = 0; nf < 4; ++nf)
                    acc2[mf][nf] = __builtin_amdgcn_mfma_f32_16x16x32_bf16(
                        ha[mf], bw[nf], acc2[mf][nf], 0, 0, 0);
        }
    }

    // ---------------- epilogue: out = acc2 + b2 + xn (fp32) ----------------
#pragma unroll
    for (int nf = 0; nf < 4; ++nf) {
        const int oc = wn * 64 + nf * 16 + fr;
#pragma unroll
        for (int mf = 0; mf < 2; ++mf)
#pragma unroll
            for (int j = 0; j < 4; ++j) {
                const long row = m0 + wm * 32 + mf * 16 + fq * 4 + j;
                out[row * CDIM + oc] = acc2[mf][nf][j] + fb2w[nf]
                                     + xnbuf[row * CDIM + oc];
            }
    }
}

// ---------------------------------------------------------------------------
extern "C" void kernel_launch(void* const* d_in, const int* in_sizes, int n_in,
                              void* d_out, int out_size, void* d_ws, size_t ws_size,
                              hipStream_t stream)
{
    const float* x    = (const float*)d_in[0];
    const float* ln1g = (const float*)d_in[1];
    const float* ln1b = (const float*)d_in[2];
    const float* ln2g = (const float*)d_in[3];
    const float* ln2b = (const float*)d_in[4];
    const float* w1   = (const float*)d_in[5];
    const float* b1   = (const float*)d_in[6];
    const float* w2   = (const float*)d_in[7];
    const float* b2   = (const float*)d_in[8];
    float* out = (float*)d_out;

    // workspace
    char* ws = (char*)d_ws;
    float*          xnbuf = (float*)ws;                           // 134,217,728 B
    __hip_bfloat16* w1fb  = (__hip_bfloat16*)(ws + 134217728);    //     524,288 B
    __hip_bfloat16* w2fb  = (__hip_bfloat16*)(ws + 134742016);    //     524,288 B

    // fragment-major weight packs:
    frag_pack<<<128, 256, 0, stream>>>(w1, w1fb, CDIM, HDIM);   // 64 cg x 8 kk
    frag_pack<<<128, 256, 0, stream>>>(w2, w2fb, HDIM, CDIM);   // 16 cg x 32 kk

    // fused block: 2048 blocks x 512 threads, 64 rows each, 3 blocks/CU
    swin_fused<<<M_TOTAL / 64, 512, 0, stream>>>(
        x, ln1g, ln1b, ln2g, ln2b,
        (const short8*)w1fb, b1, (const short8*)w2fb, b2, xnbuf, out);
}

// Round 24
// 315.705 us; speedup vs baseline: 1.5109x; 1.5109x over previous
//
#include <hip/hip_runtime.h>
#include <hip/hip_bf16.h>

#define M_TOTAL (32 * 64 * 64)   // 131072 rows
#define CDIM 256
#define HDIM 1024

typedef float  floatx4 __attribute__((ext_vector_type(4)));
typedef short  short8  __attribute__((ext_vector_type(8)));

// ---------------------------------------------------------------------------
// frag_pack: convert fp32 weight [K][N] (row-major) into fragment-major bf16:
//   dst16B[g][kk][lane] = { src[kk*32 + (lane>>4)*8 + e][g*16 + (lane&15)] }
// so one wave's B-fragment (64 lanes x 16B) is one CONTIGUOUS 1KB block.
// ---------------------------------------------------------------------------
__global__ __launch_bounds__(256) void frag_pack(
    const float* __restrict__ src, __hip_bfloat16* __restrict__ dst,
    int K, int N)
{
    const int idx  = blockIdx.x * 256 + threadIdx.x;   // one 16B frag / thread
    const int lane = idx & 63;
    const int nkk  = K >> 5;
    const int kk   = (idx >> 6) % nkk;
    const int g    = idx / (nkk << 6);
    const int col  = g * 16 + (lane & 15);
    const int k0   = kk * 32 + (lane >> 4) * 8;
    union { short8 v; __hip_bfloat16 h[8]; } p;
#pragma unroll
    for (int e = 0; e < 8; ++e)
        p.h[e] = __float2bfloat16(src[(long)(k0 + e) * N + col]);
    ((short8*)dst)[idx] = p.v;
}

// fast GELU (tanh form), max dev vs erf-GELU ~1e-3 (validated R2-R23)
__device__ __forceinline__ float gelu_fast(float v)
{
    const float t = v * __builtin_fmaf(v * v, 0.044715f, 1.0f);
    const float e = __expf(t * -1.5957691216f);
    return v * __builtin_amdgcn_rcpf(1.0f + e);
}

// ---------------------------------------------------------------------------
// Fused Swin block — FINAL (R24 = exact R18/R22, best verified 321-325us).
//   Attention path is identity (window_reverse∘window_partition + canceling
//   rolls) -> block = x + LN1(x), then MLP with LN2 + residual, fully fused:
//   one kernel, one HBM pass (x in; xnbuf fp32 round-trip; out).
//   512 thr = 8 waves (1x8 col-groups), M-tile 64, hidden chunk 128.
//   LDS = As 32KB + single Hs 16KB = 48KB -> 3 blocks/CU = 6 waves/SIMD.
//   Fragment-major weights (R16: 16-line scatter -> 1KB coalesced burst).
//   2 barriers/chunk; launch_bounds(512,4) = only allocator-stable point.
// Closed levers (counter-documented): occupancy (3blk max), bank-pad
// (worsens 3x), VGPR-cap dials ((512,2) occ-loss / (512,6) 40-VGPR storm),
// reg-prefetch (sink / asm-spill / burst-spill), producer-consumer
// (union-spill), 2x4 wave re-tile (live-set spill, +630MB scratch).
// Compiler pins 64 VGPR; residual gap to the 66us MFMA floor is the serial
// FC1->GELU->FC2 chain x JIT L2 weight latency.
// Frag conventions verified R1-R23: A/B k-map slot=kf*4+fq, elem k&7,
// row/col=fr; C/D col=lane&15, row=(lane>>4)*4+reg.
// ---------------------------------------------------------------------------
__global__ __launch_bounds__(512, 4) void swin_fused(
    const float* __restrict__ x,
    const float* __restrict__ ln1g, const float* __restrict__ ln1b,
    const float* __restrict__ ln2g, const float* __restrict__ ln2b,
    const short8* __restrict__ w1f, const float* __restrict__ fb1,
    const short8* __restrict__ w2f, const float* __restrict__ fb2,
    float* __restrict__ xnbuf, float* __restrict__ out)
{
    __shared__ __align__(16) __hip_bfloat16 As[16384];   // 32 KB [slot32][row64][8]
    __shared__ __align__(16) __hip_bfloat16 Hs[8192];    // 16 KB [slot16][row64][8]

    const int  tid = threadIdx.x;
    const long m0  = (long)blockIdx.x * 64;

    // ---------------- LN phase: 8 threads per row ----------
    {
        const int row  = tid >> 3;        // 0..63
        const int part = tid & 7;         // 32-element segment
        const float* xr = x + (m0 + row) * CDIM + part * 32;

        float4 v[8];
        float s = 0.f, sq = 0.f;
#pragma unroll
        for (int i = 0; i < 8; ++i) {
            v[i] = ((const float4*)xr)[i];
            s  += v[i].x + v[i].y + v[i].z + v[i].w;
            sq += v[i].x*v[i].x + v[i].y*v[i].y + v[i].z*v[i].z + v[i].w*v[i].w;
        }
        s  += __shfl_xor(s, 1);  s  += __shfl_xor(s, 2);  s  += __shfl_xor(s, 4);
        sq += __shfl_xor(sq, 1); sq += __shfl_xor(sq, 2); sq += __shfl_xor(sq, 4);
        const float mu = s * (1.f / CDIM);
        const float rs = rsqrtf(sq * (1.f / CDIM) - mu * mu + 1e-5f);

        float s2 = 0.f, q2 = 0.f;
        float* xnp = xnbuf + (m0 + row) * CDIM + part * 32;
#pragma unroll
        for (int i = 0; i < 8; ++i) {
            const float4 G = ((const float4*)(ln1g + part * 32))[i];
            const float4 B = ((const float4*)(ln1b + part * 32))[i];
            v[i].x += (v[i].x - mu) * rs * G.x + B.x;
            v[i].y += (v[i].y - mu) * rs * G.y + B.y;
            v[i].z += (v[i].z - mu) * rs * G.z + B.z;
            v[i].w += (v[i].w - mu) * rs * G.w + B.w;
            s2 += v[i].x + v[i].y + v[i].z + v[i].w;
            q2 += v[i].x*v[i].x + v[i].y*v[i].y + v[i].z*v[i].z + v[i].w*v[i].w;
            ((float4*)xnp)[i] = v[i];
        }
        s2 += __shfl_xor(s2, 1); s2 += __shfl_xor(s2, 2); s2 += __shfl_xor(s2, 4);
        q2 += __shfl_xor(q2, 1); q2 += __shfl_xor(q2, 2); q2 += __shfl_xor(q2, 4);
        const float mu2 = s2 * (1.f / CDIM);
        const float rs2 = rsqrtf(q2 * (1.f / CDIM) - mu2 * mu2 + 1e-5f);

        // ln2 -> As fragment layout: slot=(k>>5)*4+((k>>3)&3), elem k&7
#pragma unroll
        for (int i = 0; i < 8; ++i) {
            const int col0 = part * 32 + i * 4;
            const float4 G = ((const float4*)(ln2g + part * 32))[i];
            const float4 B = ((const float4*)(ln2b + part * 32))[i];
            union { ushort4 u; __hip_bfloat16 h[4]; } p;
            p.h[0] = __float2bfloat16((v[i].x - mu2) * rs2 * G.x + B.x);
            p.h[1] = __float2bfloat16((v[i].y - mu2) * rs2 * G.y + B.y);
            p.h[2] = __float2bfloat16((v[i].z - mu2) * rs2 * G.z + B.z);
            p.h[3] = __float2bfloat16((v[i].w - mu2) * rs2 * G.w + B.w);
            const int idx16 = ((col0 >> 5) * 4 + ((col0 >> 3) & 3)) * 64 + row;
            *(ushort4*)(As + idx16 * 8 + (col0 & 7)) = p.u;
        }
    }
    __syncthreads();

    // ---------------- MLP phase (8 chunks of 128 hidden cols) -------------
    const int wn = tid >> 6;            // wave 0..7 = col-group
    const int lane = tid & 63;
    const int fr = lane & 15, fq = lane >> 4;

    floatx4 acc2[4][2] = {};            // 64 rows x 32 out-cols per wave

    float fb2w[2];
#pragma unroll
    for (int nf = 0; nf < 2; ++nf) fb2w[nf] = fb2[wn * 32 + nf * 16 + fr];

    // fragment-major bases:
    //   fc1 frag (chunk c, kf): w1f[((c*8 + wn)*8 + kf)*64 + lane]
    //   fc2 frag (chunk c, kf, nf): w2f[((wn*2+nf)*32 + c*4 + kf)*64 + lane]

#pragma unroll 2
    for (int c = 0; c < 8; ++c) {
        // ---- fc1: coalesced frag loads inside the MFMA loop ----
        const short8* p1 = w1f + ((c * 8 + wn) * 8) * 64 + lane;
        const float bb1 = fb1[c * 128 + wn * 16 + fr];

        floatx4 acc1[4];
#pragma unroll
        for (int mf = 0; mf < 4; ++mf) acc1[mf] = (floatx4){0.f, 0.f, 0.f, 0.f};
#pragma unroll
        for (int kf = 0; kf < 8; ++kf) {
            const short8 b = p1[kf * 64];
            short8 a[4];
#pragma unroll
            for (int mf = 0; mf < 4; ++mf)
                a[mf] = *(const short8*)(As + ((kf * 4 + fq) * 64 + mf * 16 + fr) * 8);
#pragma unroll
            for (int mf = 0; mf < 4; ++mf)
                acc1[mf] = __builtin_amdgcn_mfma_f32_16x16x32_bf16(
                    a[mf], b, acc1[mf], 0, 0, 0);
        }

        __syncthreads();   // all waves' FC2(c-1) Hs reads complete

        // ---- GELU + bias -> Hs (col = wn*16+fr) ----
        {
            const int col = wn * 16 + fr;
            __hip_bfloat16* hp =
                Hs + (((col >> 5) * 4 + ((col >> 3) & 3)) * 64) * 8 + (col & 7);
#pragma unroll
            for (int mf = 0; mf < 4; ++mf)
#pragma unroll
                for (int j = 0; j < 4; ++j) {
                    const int row = mf * 16 + fq * 4 + j;
                    hp[row * 8] = __float2bfloat16(gelu_fast(acc1[mf][j] + bb1));
                }
        }
        __syncthreads();   // Hs ready for all waves

        // ---- fc2 partial: coalesced frag loads, 8 MFMA/kf into acc2 ----
#pragma unroll
        for (int kf = 0; kf < 4; ++kf) {
            short8 bw[2];
#pragma unroll
            for (int nf = 0; nf < 2; ++nf)
                bw[nf] = w2f[((wn * 2 + nf) * 32 + c * 4 + kf) * 64 + lane];
            short8 ha[4];
#pragma unroll
            for (int mf = 0; mf < 4; ++mf)
                ha[mf] = *(const short8*)(Hs + ((kf * 4 + fq) * 64 + mf * 16 + fr) * 8);
#pragma unroll
            for (int mf = 0; mf < 4; ++mf)
#pragma unroll
                for (int nf = 0; nf < 2; ++nf)
                    acc2[mf][nf] = __builtin_amdgcn_mfma_f32_16x16x32_bf16(
                        ha[mf], bw[nf], acc2[mf][nf], 0, 0, 0);
        }
    }

    // ---------------- epilogue: out = acc2 + b2 + xn (fp32) ----------------
#pragma unroll
    for (int nf = 0; nf < 2; ++nf) {
        const int oc = wn * 32 + nf * 16 + fr;
#pragma unroll
        for (int mf = 0; mf < 4; ++mf)
#pragma unroll
            for (int j = 0; j < 4; ++j) {
                const long row = m0 + mf * 16 + fq * 4 + j;
                out[row * CDIM + oc] = acc2[mf][nf][j] + fb2w[nf]
                                     + xnbuf[row * CDIM + oc];
            }
    }
}

// ---------------------------------------------------------------------------
extern "C" void kernel_launch(void* const* d_in, const int* in_sizes, int n_in,
                              void* d_out, int out_size, void* d_ws, size_t ws_size,
                              hipStream_t stream)
{
    const float* x    = (const float*)d_in[0];
    const float* ln1g = (const float*)d_in[1];
    const float* ln1b = (const float*)d_in[2];
    const float* ln2g = (const float*)d_in[3];
    const float* ln2b = (const float*)d_in[4];
    const float* w1   = (const float*)d_in[5];
    const float* b1   = (const float*)d_in[6];
    const float* w2   = (const float*)d_in[7];
    const float* b2   = (const float*)d_in[8];
    float* out = (float*)d_out;

    // workspace
    char* ws = (char*)d_ws;
    float*          xnbuf = (float*)ws;                           // 134,217,728 B
    __hip_bfloat16* w1fb  = (__hip_bfloat16*)(ws + 134217728);    //     524,288 B
    __hip_bfloat16* w2fb  = (__hip_bfloat16*)(ws + 134742016);    //     524,288 B

    // fragment-major weight packs:
    frag_pack<<<128, 256, 0, stream>>>(w1, w1fb, CDIM, HDIM);   // 64 cg x 8 kk
    frag_pack<<<128, 256, 0, stream>>>(w2, w2fb, HDIM, CDIM);   // 16 cg x 32 kk

    // fused block: 2048 blocks x 512 threads, 64 rows each, 3 blocks/CU
    swin_fused<<<M_TOTAL / 64, 512, 0, stream>>>(
        x, ln1g, ln1b, ln2g, ln2b,
        (const short8*)w1fb, b1, (const short8*)w2fb, b2, xnbuf, out);
}